// Round 3
// baseline (461.242 us; speedup 1.0000x reference)
//
#include <hip/hip_runtime.h>

// Problem constants (reference: DIM=64, WIRES=3, INDEX=1, BATCH=128)
#define DIMQ   64
#define NCOLS  8192            // right * batch = 64*128
#define SLAB   (DIMQ * NCOLS)  // per-a elements = 524288
#define NA     64              // left = dim^index
#define DB     (NA * SLAB)     // D*B = 33554432

// LDS staging layout (per array): 64 rows x 64 cols fp32, stored as 16 chunks
// of 4 rows. Chunk p lives at byte offset p*CHUNKB; row r (global) is chunk
// r>>2, sub-row r&3 at (r&3)*256B; col c at c*4B. The +16B stagger per chunk
// makes fragment reads 2-way bank-aliased (free) instead of 4-way.
#define CHUNKB 1040            // 1024 + 16 stagger
#define NCHUNK 16
#define ARRB   (NCHUNK * CHUNKB)   // 16640 B per array; 2 arrays = 33280 B

typedef __attribute__((ext_vector_type(8))) __bf16 bf16x8;
typedef __attribute__((ext_vector_type(8))) unsigned short us8;
typedef __attribute__((ext_vector_type(4))) float f32x4;

__device__ __forceinline__ unsigned short f2bf(float f) {
    unsigned u = __builtin_bit_cast(unsigned, f);
    unsigned r = u + 0x7fffu + ((u >> 16) & 1u);   // RNE to bf16
    return (unsigned short)(r >> 16);
}

// Load M A-fragments (A[m=l15][k=q*8+j]) for all 4 i-tiles / 2 k-blocks.
__device__ __forceinline__ void load_M_frags(
    const float* __restrict__ Mr, const float* __restrict__ Mi,
    int l15, int q, bf16x8 fMr[4][2], bf16x8 fMi[4][2])
{
#pragma unroll
    for (int it = 0; it < 4; ++it) {
#pragma unroll
        for (int kb = 0; kb < 2; ++kb) {
            const int row = it * 16 + l15;
            const int col = kb * 32 + q * 8;
            const float* pr = Mr + row * DIMQ + col;
            const float* pi = Mi + row * DIMQ + col;
            us8 hr, hi;
#pragma unroll
            for (int j = 0; j < 8; ++j) {
                hr[j] = f2bf(pr[j]);
                hi[j] = f2bf(pi[j]);
            }
            fMr[it][kb] = __builtin_bit_cast(bf16x8, hr);
            fMi[it][kb] = __builtin_bit_cast(bf16x8, hi);
        }
    }
}

// ---- Variant A: output = Re(y) only. 256 threads (4 waves) per block.
// Block = one (a, 64-col chunk). LDS-staged X via global_load_lds width 16.
__global__ __launch_bounds__(256, 4) void gate_real_v2(
    const float* __restrict__ Mr, const float* __restrict__ Mi,
    const float* __restrict__ Xr, const float* __restrict__ Xi,
    float* __restrict__ Out)
{
    __shared__ __align__(16) char lds[2 * ARRB];

    const int tid  = threadIdx.x;
    const int lane = tid & 63;
    const int w    = tid >> 6;        // wave 0..3
    const int l15  = lane & 15;
    const int q    = lane >> 4;

    const int bid   = blockIdx.x;     // 8192 = 64 a * 128 chunks
    const int a     = bid >> 7;
    const int chunk = bid & 127;
    const int n0blk = chunk * 64;
    const size_t baseA = (size_t)a * SLAB;

    // ---- stage Xr/Xi tile (64 rows x 64 cols) into LDS, 8 instrs/wave ----
    {
        const float* gR = Xr + baseA + n0blk;
        const float* gI = Xi + baseA + n0blk;
        char* ldsR = lds;
        char* ldsI = lds + ARRB;
#pragma unroll
        for (int pl = 0; pl < 4; ++pl) {
            const int p   = w * 4 + pl;            // chunk 0..15 (4 rows each)
            const int row = p * 4 + (lane >> 4);   // this lane's global row
            const size_t goff = (size_t)row * NCOLS + (size_t)(lane & 15) * 4;
            __builtin_amdgcn_global_load_lds(
                (const __attribute__((address_space(1))) void*)(gR + goff),
                (__attribute__((address_space(3))) void*)(ldsR + p * CHUNKB),
                16, 0, 0);
            __builtin_amdgcn_global_load_lds(
                (const __attribute__((address_space(1))) void*)(gI + goff),
                (__attribute__((address_space(3))) void*)(ldsI + p * CHUNKB),
                16, 0, 0);
        }
    }

    // M fragments from L2 — issued while the LDS staging is in flight.
    bf16x8 fMr[4][2], fMi[4][2];
    load_M_frags(Mr, Mi, l15, q, fMr, fMi);

    __syncthreads();   // compiler emits s_waitcnt vmcnt(0) before s_barrier

    // ---- compute: wave w owns cols [w*16, w*16+16) of the staged tile ----
    const int c = w * 16 + l15;       // LDS-local column
    f32x4 acc[4] = {f32x4{0,0,0,0}, f32x4{0,0,0,0}, f32x4{0,0,0,0}, f32x4{0,0,0,0}};

#pragma unroll
    for (int kb = 0; kb < 2; ++kb) {
        const int k0 = kb * 32 + q * 8;
        float fr[8], fi[8];
#pragma unroll
        for (int j = 0; j < 8; ++j) {
            const int k   = k0 + j;
            const int off = (k >> 2) * CHUNKB + (k & 3) * 256 + c * 4;
            fr[j] = *(const float*)(lds + off);
            fi[j] = *(const float*)(lds + ARRB + off);
        }
        us8 hr, hni;
#pragma unroll
        for (int j = 0; j < 8; ++j) {
            hr[j]  = f2bf(fr[j]);
            hni[j] = (unsigned short)(f2bf(fi[j]) ^ 0x8000u);   // -Xi
        }
        const bf16x8 bXr  = __builtin_bit_cast(bf16x8, hr);
        const bf16x8 bXni = __builtin_bit_cast(bf16x8, hni);

#pragma unroll
        for (int it = 0; it < 4; ++it) {
            acc[it] = __builtin_amdgcn_mfma_f32_16x16x32_bf16(fMr[it][kb], bXr,  acc[it], 0, 0, 0);
            acc[it] = __builtin_amdgcn_mfma_f32_16x16x32_bf16(fMi[it][kb], bXni, acc[it], 0, 0, 0);
        }
    }

    // ---- store: C/D layout col=l15 (-> n), row=q*4+r (-> i) ----
#pragma unroll
    for (int it = 0; it < 4; ++it) {
#pragma unroll
        for (int r = 0; r < 4; ++r) {
            const int i = it * 16 + q * 4 + r;
            Out[baseA + (size_t)i * NCOLS + n0blk + c] = acc[it][r];
        }
    }
}

// ---- Variant B (safety fallback): interleaved complex64, out_size = 2*D*B ----
__global__ __launch_bounds__(64, 2) void gate_cplx_kernel(
    const float* __restrict__ Mr, const float* __restrict__ Mi,
    const float* __restrict__ Xr, const float* __restrict__ Xi,
    float* __restrict__ Out)
{
    const int lane = threadIdx.x;
    const int l15  = lane & 15;
    const int q    = lane >> 4;

    bf16x8 fMr[4][2], fMi[4][2];
    load_M_frags(Mr, Mi, l15, q, fMr, fMi);

    const int bid = blockIdx.x;
    const int a   = bid >> 6;
    const int nch = bid & 63;
    const size_t baseA = (size_t)a * SLAB;

    for (int tt = 0; tt < 8; ++tt) {
        const int n0 = nch * 128 + tt * 16;
        f32x4 accR[4] = {f32x4{0,0,0,0}, f32x4{0,0,0,0}, f32x4{0,0,0,0}, f32x4{0,0,0,0}};
        f32x4 accI[4] = {f32x4{0,0,0,0}, f32x4{0,0,0,0}, f32x4{0,0,0,0}, f32x4{0,0,0,0}};

#pragma unroll
        for (int kb = 0; kb < 2; ++kb) {
            const int krow = kb * 32 + q * 8;
            const float* pr = Xr + baseA + (size_t)krow * NCOLS + n0 + l15;
            const float* pi = Xi + baseA + (size_t)krow * NCOLS + n0 + l15;
            float fr[8], fi[8];
#pragma unroll
            for (int j = 0; j < 8; ++j) {
                fr[j] = pr[(size_t)j * NCOLS];
                fi[j] = pi[(size_t)j * NCOLS];
            }
            us8 hr, hi, hni;
#pragma unroll
            for (int j = 0; j < 8; ++j) {
                hr[j] = f2bf(fr[j]);
                const unsigned short t = f2bf(fi[j]);
                hi[j]  = t;
                hni[j] = (unsigned short)(t ^ 0x8000u);
            }
            const bf16x8 bXr  = __builtin_bit_cast(bf16x8, hr);
            const bf16x8 bXi  = __builtin_bit_cast(bf16x8, hi);
            const bf16x8 bXni = __builtin_bit_cast(bf16x8, hni);

#pragma unroll
            for (int it = 0; it < 4; ++it) {
                accR[it] = __builtin_amdgcn_mfma_f32_16x16x32_bf16(fMr[it][kb], bXr,  accR[it], 0, 0, 0);
                accR[it] = __builtin_amdgcn_mfma_f32_16x16x32_bf16(fMi[it][kb], bXni, accR[it], 0, 0, 0);
                accI[it] = __builtin_amdgcn_mfma_f32_16x16x32_bf16(fMr[it][kb], bXi,  accI[it], 0, 0, 0);
                accI[it] = __builtin_amdgcn_mfma_f32_16x16x32_bf16(fMi[it][kb], bXr,  accI[it], 0, 0, 0);
            }
        }

#pragma unroll
        for (int it = 0; it < 4; ++it) {
#pragma unroll
            for (int r = 0; r < 4; ++r) {
                const int i = it * 16 + q * 4 + r;
                const size_t cidx = baseA + (size_t)i * NCOLS + n0 + l15;
                float2 v;
                v.x = accR[it][r];
                v.y = accI[it][r];
                reinterpret_cast<float2*>(Out)[cidx] = v;
            }
        }
    }
}

extern "C" void kernel_launch(void* const* d_in, const int* in_sizes, int n_in,
                              void* d_out, int out_size, void* d_ws, size_t ws_size,
                              hipStream_t stream) {
    const float* Mr = (const float*)d_in[0];
    const float* Mi = (const float*)d_in[1];
    const float* Xr = (const float*)d_in[2];
    const float* Xi = (const float*)d_in[3];
    float* Out = (float*)d_out;

    if (out_size >= 2 * DB) {
        dim3 grid(NA * 64);
        dim3 block(64);
        gate_cplx_kernel<<<grid, block, 0, stream>>>(Mr, Mi, Xr, Xi, Out);
    } else {
        dim3 grid(NA * 128);   // 64 a-slabs * 128 col-chunks (64 cols each)
        dim3 block(256);
        gate_real_v2<<<grid, block, 0, stream>>>(Mr, Mi, Xr, Xi, Out);
    }
}

// Round 4
// 412.803 us; speedup vs baseline: 1.1173x; 1.1173x over previous
//
#include <hip/hip_runtime.h>

// Problem constants (reference: DIM=64, WIRES=3, INDEX=1, BATCH=128)
#define DIMQ   64
#define NCOLS  8192            // right * batch = 64*128
#define SLAB   (DIMQ * NCOLS)  // per-a elements = 524288
#define NA     64              // left = dim^index
#define DB     (NA * SLAB)     // D*B = 33554432

#define PADT   68              // transpose-buffer row stride (floats): bank=(4i+c)%32 -> 2-way

typedef __attribute__((ext_vector_type(8))) __bf16 bf16x8;
typedef __attribute__((ext_vector_type(8))) unsigned short us8;
typedef __attribute__((ext_vector_type(4))) float f32x4;

__device__ __forceinline__ unsigned short f2bf(float f) {
    unsigned u = __builtin_bit_cast(unsigned, f);
    unsigned r = u + 0x7fffu + ((u >> 16) & 1u);   // RNE to bf16
    return (unsigned short)(r >> 16);
}

// Load M A-fragments (A[m=l15][k=q*8+j]) for all 4 i-tiles / 2 k-blocks.
__device__ __forceinline__ void load_M_frags(
    const float* __restrict__ Mr, const float* __restrict__ Mi,
    int l15, int q, bf16x8 fMr[4][2], bf16x8 fMi[4][2])
{
#pragma unroll
    for (int it = 0; it < 4; ++it) {
#pragma unroll
        for (int kb = 0; kb < 2; ++kb) {
            const int row = it * 16 + l15;
            const int col = kb * 32 + q * 8;
            const float* pr = Mr + row * DIMQ + col;
            const float* pi = Mi + row * DIMQ + col;
            us8 hr, hi;
#pragma unroll
            for (int j = 0; j < 8; ++j) {
                hr[j] = f2bf(pr[j]);
                hi[j] = f2bf(pi[j]);
            }
            fMr[it][kb] = __builtin_bit_cast(bf16x8, hr);
            fMi[it][kb] = __builtin_bit_cast(bf16x8, hi);
        }
    }
}

// Variant A: Re(y) only. 256 threads / 4 waves per block.
// Block = (a, 64-col chunk). Stage Xr/Xi (64x64 fp32) via global_load_lds w16,
// MFMA per-wave on one 16-col n-tile, then LDS-transpose the accumulators and
// store full 128-B lines (float4 per lane, 256 B contiguous per row).
__global__ __launch_bounds__(256, 4) void gate_real_v3(
    const float* __restrict__ Mr, const float* __restrict__ Mi,
    const float* __restrict__ Xr, const float* __restrict__ Xi,
    float* __restrict__ Out)
{
    // 32 KB: Xr tile [0,4096) floats, Xi tile [4096,8192) floats.
    // Transpose buffer (64 x PADT floats = 17408 B) reuses the same region.
    __shared__ __align__(16) float lds[2 * 4096];

    const int tid  = threadIdx.x;
    const int lane = tid & 63;
    const int w    = tid >> 6;        // wave 0..3
    const int l15  = lane & 15;
    const int q    = lane >> 4;

    const int bid   = blockIdx.x;     // 8192 = 64 a * 128 chunks
    const int a     = bid >> 7;
    const int chunk = bid & 127;
    const int n0blk = chunk * 64;
    const size_t baseA = (size_t)a * SLAB;

    // ---- stage Xr/Xi 64x64 tile into LDS: 16 x 1KB instrs per array ----
    {
        const float* gR = Xr + baseA + n0blk;
        const float* gI = Xi + baseA + n0blk;
#pragma unroll
        for (int pl = 0; pl < 4; ++pl) {
            const int p = w * 4 + pl;                       // 0..15, 4 rows each
            const size_t goff = (size_t)(4 * p + (lane >> 4)) * NCOLS
                              + (size_t)(lane & 15) * 4;    // float4 per lane
            __builtin_amdgcn_global_load_lds(
                (const __attribute__((address_space(1))) void*)(gR + goff),
                (__attribute__((address_space(3))) void*)((char*)lds + p * 1024),
                16, 0, 0);
            __builtin_amdgcn_global_load_lds(
                (const __attribute__((address_space(1))) void*)(gI + goff),
                (__attribute__((address_space(3))) void*)((char*)lds + 16384 + p * 1024),
                16, 0, 0);
        }
    }

    // M fragments from L2 — issued while staging is in flight.
    bf16x8 fMr[4][2], fMi[4][2];
    load_M_frags(Mr, Mi, l15, q, fMr, fMi);

    __syncthreads();   // drains vmcnt before barrier

    // ---- compute: wave w owns n-tile cols [w*16, w*16+16) ----
    const int c = w * 16 + l15;
    f32x4 acc[4] = {f32x4{0,0,0,0}, f32x4{0,0,0,0}, f32x4{0,0,0,0}, f32x4{0,0,0,0}};

#pragma unroll
    for (int kb = 0; kb < 2; ++kb) {
        const int k0 = kb * 32 + q * 8;
        float fr[8], fi[8];
#pragma unroll
        for (int j = 0; j < 8; ++j) {
            const int k = k0 + j;
            fr[j] = lds[k * 64 + c];
            fi[j] = lds[4096 + k * 64 + c];
        }
        us8 hr, hni;
#pragma unroll
        for (int j = 0; j < 8; ++j) {
            hr[j]  = f2bf(fr[j]);
            hni[j] = (unsigned short)(f2bf(fi[j]) ^ 0x8000u);   // -Xi
        }
        const bf16x8 bXr  = __builtin_bit_cast(bf16x8, hr);
        const bf16x8 bXni = __builtin_bit_cast(bf16x8, hni);

#pragma unroll
        for (int it = 0; it < 4; ++it) {
            acc[it] = __builtin_amdgcn_mfma_f32_16x16x32_bf16(fMr[it][kb], bXr,  acc[it], 0, 0, 0);
            acc[it] = __builtin_amdgcn_mfma_f32_16x16x32_bf16(fMi[it][kb], bXni, acc[it], 0, 0, 0);
        }
    }

    __syncthreads();   // all frag reads done; safe to overwrite staging region

    // ---- transpose: acc (C/D layout col=l15, row=q*4+r) -> row-major buf ----
#pragma unroll
    for (int it = 0; it < 4; ++it) {
#pragma unroll
        for (int r = 0; r < 4; ++r) {
            const int i = it * 16 + q * 4 + r;
            lds[i * PADT + c] = acc[it][r];
        }
    }

    __syncthreads();

    // ---- store: full lines. Each instr: 4 rows x 256 B contiguous ----
#pragma unroll
    for (int rr = 0; rr < 4; ++rr) {
        const int row = w * 16 + rr * 4 + (lane >> 4);
        const int g   = lane & 15;
        const float4 v = *(const float4*)&lds[row * PADT + g * 4];
        *(float4*)&Out[baseA + (size_t)row * NCOLS + n0blk + g * 4] = v;
    }
}

// ---- Variant B (safety fallback): interleaved complex64, out_size = 2*D*B ----
__global__ __launch_bounds__(64, 2) void gate_cplx_kernel(
    const float* __restrict__ Mr, const float* __restrict__ Mi,
    const float* __restrict__ Xr, const float* __restrict__ Xi,
    float* __restrict__ Out)
{
    const int lane = threadIdx.x;
    const int l15  = lane & 15;
    const int q    = lane >> 4;

    bf16x8 fMr[4][2], fMi[4][2];
    load_M_frags(Mr, Mi, l15, q, fMr, fMi);

    const int bid = blockIdx.x;
    const int a   = bid >> 6;
    const int nch = bid & 63;
    const size_t baseA = (size_t)a * SLAB;

    for (int tt = 0; tt < 8; ++tt) {
        const int n0 = nch * 128 + tt * 16;
        f32x4 accR[4] = {f32x4{0,0,0,0}, f32x4{0,0,0,0}, f32x4{0,0,0,0}, f32x4{0,0,0,0}};
        f32x4 accI[4] = {f32x4{0,0,0,0}, f32x4{0,0,0,0}, f32x4{0,0,0,0}, f32x4{0,0,0,0}};

#pragma unroll
        for (int kb = 0; kb < 2; ++kb) {
            const int krow = kb * 32 + q * 8;
            const float* pr = Xr + baseA + (size_t)krow * NCOLS + n0 + l15;
            const float* pi = Xi + baseA + (size_t)krow * NCOLS + n0 + l15;
            float fr[8], fi[8];
#pragma unroll
            for (int j = 0; j < 8; ++j) {
                fr[j] = pr[(size_t)j * NCOLS];
                fi[j] = pi[(size_t)j * NCOLS];
            }
            us8 hr, hi, hni;
#pragma unroll
            for (int j = 0; j < 8; ++j) {
                hr[j] = f2bf(fr[j]);
                const unsigned short t = f2bf(fi[j]);
                hi[j]  = t;
                hni[j] = (unsigned short)(t ^ 0x8000u);
            }
            const bf16x8 bXr  = __builtin_bit_cast(bf16x8, hr);
            const bf16x8 bXi  = __builtin_bit_cast(bf16x8, hi);
            const bf16x8 bXni = __builtin_bit_cast(bf16x8, hni);

#pragma unroll
            for (int it = 0; it < 4; ++it) {
                accR[it] = __builtin_amdgcn_mfma_f32_16x16x32_bf16(fMr[it][kb], bXr,  accR[it], 0, 0, 0);
                accR[it] = __builtin_amdgcn_mfma_f32_16x16x32_bf16(fMi[it][kb], bXni, accR[it], 0, 0, 0);
                accI[it] = __builtin_amdgcn_mfma_f32_16x16x32_bf16(fMr[it][kb], bXi,  accI[it], 0, 0, 0);
                accI[it] = __builtin_amdgcn_mfma_f32_16x16x32_bf16(fMi[it][kb], bXr,  accI[it], 0, 0, 0);
            }
        }

#pragma unroll
        for (int it = 0; it < 4; ++it) {
#pragma unroll
            for (int r = 0; r < 4; ++r) {
                const int i = it * 16 + q * 4 + r;
                const size_t cidx = baseA + (size_t)i * NCOLS + n0 + l15;
                float2 v;
                v.x = accR[it][r];
                v.y = accI[it][r];
                reinterpret_cast<float2*>(Out)[cidx] = v;
            }
        }
    }
}

extern "C" void kernel_launch(void* const* d_in, const int* in_sizes, int n_in,
                              void* d_out, int out_size, void* d_ws, size_t ws_size,
                              hipStream_t stream) {
    const float* Mr = (const float*)d_in[0];
    const float* Mi = (const float*)d_in[1];
    const float* Xr = (const float*)d_in[2];
    const float* Xi = (const float*)d_in[3];
    float* Out = (float*)d_out;

    if (out_size >= 2 * DB) {
        dim3 grid(NA * 64);
        dim3 block(64);
        gate_cplx_kernel<<<grid, block, 0, stream>>>(Mr, Mi, Xr, Xi, Out);
    } else {
        dim3 grid(NA * 128);   // 64 a-slabs * 128 col-chunks (64 cols each)
        dim3 block(256);
        gate_real_v3<<<grid, block, 0, stream>>>(Mr, Mi, Xr, Xi, Out);
    }
}